// Round 3
// baseline (177.800 us; speedup 1.0000x reference)
//
#include <hip/hip_runtime.h>
#include <math.h>

// N=4, R=16384, K=96. Output: rgb [65536*3] | depth [65536] | weights [65536*95]
#define NRAYS     65536
#define KM1       95
#define RGB_OFF   0
#define DEPTH_OFF (NRAYS * 3)
#define W_OFF     (NRAYS * 4)

// 16B vector store with only 4B guaranteed alignment (weights rows are
// ray*95 floats apart). gfx950 supports dword-aligned multi-dword stores;
// worst case the compiler splits it into 4 dword stores.
typedef float f4u __attribute__((ext_vector_type(4), aligned(4)));

// 1-alpha = exp(-delta*softplus(x)) via HW transcendentals:
// 2^(-delta*log2(1+2^(x*log2e))); 3 quarter-rate ops instead of libm.
__device__ __forceinline__ float one_minus_alpha(float x, float delta) {
    const float L2E = 1.44269504088896340736f;
    float xl = x * L2E;
    float l2 = (x > 20.0f) ? xl
                           : __builtin_amdgcn_logf(1.0f + __builtin_amdgcn_exp2f(xl));
    return __builtin_amdgcn_exp2f(-delta * l2);
}

// ---------------------------------------------------------------------------
// 4 lanes per ray; lane (t&3)=s integrates samples [24s, 24s+24) sequentially
// in registers (running transmittance product -- no per-interval cross-lane).
// Segment results combine with a 3-shfl prefix product and a 2-step shfl
// butterfly: composite sums factor as T_in(s) * Sum_local(alpha*T_loc*f).
// Per-interval weights live in u[24] VGPRs, scaled by T_in at the end.
// ---------------------------------------------------------------------------
__global__ __launch_bounds__(256) void integrate_kernel(
    const float* __restrict__ rgbs,     // [NRAYS, 96, 3]
    const float* __restrict__ sigmas,   // [NRAYS, 96]
    const float* __restrict__ depths,   // [NRAYS, 96]
    float* __restrict__ out)
{
    const int t   = threadIdx.x;
    const int seg = t & 3;
    const int ray = blockIdx.x * 64 + (t >> 2);

    const float* db = depths + ray * 96  + seg * 24;   // 16B aligned (96B step)
    const float* sb = sigmas + ray * 96  + seg * 24;
    const float* rb = rgbs   + ray * 288 + seg * 72;   // 16B aligned (288B step)

    float u[24];
    float Tloc = 1.0f;
    float Sw = 0.f, Sd = 0.f, Sr = 0.f, Sg = 0.f, Sb = 0.f;
    float d0f=0.f, s0f=0.f, r0f=0.f, g0f=0.f, b0f=0.f, d1f=0.f, dpen=0.f;
    float dp=0.f, sp=0.f, rp=0.f, gp=0.f, bp=0.f;   // previous sample carry

#define DO_IV(IDX, dA,sA,rA,gA,bA, dB,sB,rB,gB,bB)                 \
    { float delta = (dB) - (dA);                                   \
      float x = 0.5f * ((sA) + (sB)) - 1.0f;                       \
      float e = one_minus_alpha(x, delta);                         \
      float uu = (1.0f - e) * Tloc;                                \
      Tloc *= e + 1e-10f;                                          \
      u[IDX] = uu;                                                 \
      Sw += uu;                                                    \
      Sd += uu * (0.5f * ((dA) + (dB)));                           \
      Sr += uu * (0.5f * ((rA) + (rB)));                           \
      Sg += uu * (0.5f * ((gA) + (gB)));                           \
      Sb += uu * (0.5f * ((bA) + (bB))); }

    #pragma unroll
    for (int j = 0; j < 6; ++j) {
        float4 d4 = *(const float4*)(db + 4*j);
        float4 s4 = *(const float4*)(sb + 4*j);
        float4 r0 = *(const float4*)(rb + 12*j);
        float4 r1 = *(const float4*)(rb + 12*j + 4);
        float4 r2 = *(const float4*)(rb + 12*j + 8);
        // samples in this chunk: (d4.x,s4.x,r0.xyz) (d4.y,s4.y,r0.w,r1.xy)
        //                        (d4.z,s4.z,r1.zw,r2.x) (d4.w,s4.w,r2.yzw)
        if (j == 0) {
            d0f=d4.x; s0f=s4.x; r0f=r0.x; g0f=r0.y; b0f=r0.z; d1f=d4.y;
        } else {
            DO_IV(4*j-1, dp,sp,rp,gp,bp, d4.x,s4.x,r0.x,r0.y,r0.z);
        }
        DO_IV(4*j+0, d4.x,s4.x,r0.x,r0.y,r0.z,  d4.y,s4.y,r0.w,r1.x,r1.y);
        DO_IV(4*j+1, d4.y,s4.y,r0.w,r1.x,r1.y,  d4.z,s4.z,r1.z,r1.w,r2.x);
        DO_IV(4*j+2, d4.z,s4.z,r1.z,r1.w,r2.x,  d4.w,s4.w,r2.y,r2.z,r2.w);
        if (j == 5) dpen = d4.z;
        dp=d4.w; sp=s4.w; rp=r2.y; gp=r2.z; bp=r2.w;
    }

    // boundary interval (local 23): last sample here -> next segment's first
    // sample, fetched from lane+1 (seg3 has only 23 intervals: 72..94).
    float dn = __shfl_down(d0f, 1);
    float sn = __shfl_down(s0f, 1);
    float rn = __shfl_down(r0f, 1);
    float gn = __shfl_down(g0f, 1);
    float bn = __shfl_down(b0f, 1);
    if (seg < 3) {
        DO_IV(23, dp,sp,rp,gp,bp, dn,sn,rn,gn,bn);
    } else {
        u[23] = 0.0f;
    }

    // exclusive prefix product of segment transmittances within each 4-lane group
    float incl = Tloc;
    float p1 = __shfl_up(incl, 1); if (seg >= 1) incl *= p1;
    float p2 = __shfl_up(incl, 2); if (seg >= 2) incl *= p2;
    float Tin = __shfl_up(incl, 1);
    if (seg == 0) Tin = 1.0f;

    Sw *= Tin; Sd *= Tin; Sr *= Tin; Sg *= Tin; Sb *= Tin;
    #pragma unroll
    for (int off = 1; off <= 2; off <<= 1) {   // xor-1, xor-2: sums within group of 4
        Sw += __shfl_xor(Sw, off);
        Sd += __shfl_xor(Sd, off);
        Sr += __shfl_xor(Sr, off);
        Sg += __shfl_xor(Sg, off);
        Sb += __shfl_xor(Sb, off);
    }

    // weights output [ray][i], segment covers i in [24*seg, 24*seg+24) (23 for seg3)
    float* wout = out + W_OFF + ray * 95 + seg * 24;
    if (seg < 3) {
        #pragma unroll
        for (int k = 0; k < 6; ++k) {
            f4u v = { Tin*u[4*k], Tin*u[4*k+1], Tin*u[4*k+2], Tin*u[4*k+3] };
            *(f4u*)(wout + 4*k) = v;
        }
    } else {
        #pragma unroll
        for (int k = 0; k < 5; ++k) {
            f4u v = { Tin*u[4*k], Tin*u[4*k+1], Tin*u[4*k+2], Tin*u[4*k+3] };
            *(f4u*)(wout + 4*k) = v;
        }
        wout[20] = Tin*u[20];
        wout[21] = Tin*u[21];
        wout[22] = Tin*u[22];
    }

    // per-ray outputs from the seg==0 lane; depth clipped to ray-local midpoint
    // range (convex combination => identical to the reference's global clip)
    float hiloc = 0.5f * (dpen + dp);            // 0.5*(d[94]+d[95]), valid on seg3
    const int lane = t & 63;
    float hi = __shfl(hiloc, lane | 3);
    if (seg == 0) {
        out[RGB_OFF + ray*3 + 0] = 2.f*Sr - 1.f;
        out[RGB_OFF + ray*3 + 1] = 2.f*Sg - 1.f;
        out[RGB_OFF + ray*3 + 2] = 2.f*Sb - 1.f;
        float dv = Sd / Sw;                      // normalize_depth
        float lo = 0.5f * (d0f + d1f);           // 0.5*(d[0]+d[1])
        dv = fmaxf(fminf(dv, hi), lo);           // NaN -> hi (matches nan->inf->clip)
        out[DEPTH_OFF + ray] = dv;
    }
#undef DO_IV
}

extern "C" void kernel_launch(void* const* d_in, const int* in_sizes, int n_in,
                              void* d_out, int out_size, void* d_ws, size_t ws_size,
                              hipStream_t stream) {
    const float* rgbs   = (const float*)d_in[0];
    const float* sigmas = (const float*)d_in[1];
    const float* depths = (const float*)d_in[2];
    float* out = (float*)d_out;

    // 4 lanes per ray, 64 rays per 256-thread block -> 1024 blocks
    integrate_kernel<<<NRAYS / 64, 256, 0, stream>>>(rgbs, sigmas, depths, out);
}

// Round 4
// 157.607 us; speedup vs baseline: 1.1281x; 1.1281x over previous
//
#include <hip/hip_runtime.h>
#include <math.h>

// N=4, R=16384, K=96. Output: rgb [65536*3] | depth [65536] | weights [65536*95]
#define NRAYS     65536
#define RGB_OFF   0
#define DEPTH_OFF (NRAYS * 3)
#define W_OFF     (NRAYS * 4)

typedef float f4u __attribute__((ext_vector_type(4), aligned(4)));
typedef float f2u __attribute__((ext_vector_type(2), aligned(4)));

// DPP move within a 16-lane row; invalid source lanes receive `oldv`.
// ctrl: 0x110|N = row_shr:N
#define DPPF(oldv, x, ctrl)                                                    \
    __int_as_float(__builtin_amdgcn_update_dpp(                                \
        __float_as_int(oldv), __float_as_int(x), (ctrl), 0xF, 0xF, false))

// 1-alpha = exp(-delta*softplus(x)) via HW transcendentals:
// 2^(-delta*log2(1+2^(x*log2e))). Validated absmax 7.8e-3 << 4.3e-2.
__device__ __forceinline__ float one_minus_alpha(float x, float delta) {
    const float L2E = 1.44269504088896340736f;
    float xl = x * L2E;
    float l2 = (x > 20.0f) ? xl
                           : __builtin_amdgcn_logf(1.0f + __builtin_amdgcn_exp2f(xl));
    return __builtin_amdgcn_exp2f(-delta * l2);
}

// ---------------------------------------------------------------------------
// 16 lanes per ray (one DPP row = one ray; 4 rays per wave). Lane l owns
// intervals [6l, 6l+6) (lane 15: [90,95)) and loads samples 6l..6l+6 straight
// from global -- per row the loads tile the ray contiguously (fully
// coalesced), so no LDS staging is needed. Sequential in-lane running
// transmittance; cross-lane only via DPP row_shr on the VALU pipe:
// 4-step product scan + 1 shift (T_in), 4-step add-reduce x5, 1 bcast.
// Zero LDS, zero shuffles.
// ---------------------------------------------------------------------------
__global__ __launch_bounds__(256) void integrate_kernel(
    const float* __restrict__ rgbs,     // [NRAYS, 96, 3]
    const float* __restrict__ sigmas,   // [NRAYS, 96]
    const float* __restrict__ depths,   // [NRAYS, 96]
    float* __restrict__ out)
{
    const int t    = threadIdx.x;
    const int l    = t & 15;                    // segment within the ray
    const int ray  = blockIdx.x * 16 + (t >> 4);
    const bool full = (l < 15);                 // lane 15 has 5 intervals, 6 samples

    const float* db = depths + ray * 96  + 6 * l;    // byte offset 24l: 8-aligned
    const float* sb = sigmas + ray * 96  + 6 * l;
    const float* rb = rgbs   + ray * 288 + 18 * l;   // byte offset 72l: 8-aligned

    // ---- coalesced direct global loads (float2-granule) ----
    float2 e0 = *(const float2*)(db);
    float2 e1 = *(const float2*)(db + 2);
    float2 e2 = *(const float2*)(db + 4);
    float  d6 = full ? db[6] : 0.f;
    float2 f0 = *(const float2*)(sb);
    float2 f1 = *(const float2*)(sb + 2);
    float2 f2v = *(const float2*)(sb + 4);
    float  s6 = full ? sb[6] : 0.f;
    float2 c0 = *(const float2*)(rb);
    float2 c1 = *(const float2*)(rb + 2);
    float2 c2 = *(const float2*)(rb + 4);
    float2 c3 = *(const float2*)(rb + 6);
    float2 c4 = *(const float2*)(rb + 8);
    float2 c5 = *(const float2*)(rb + 10);
    float2 c6 = *(const float2*)(rb + 12);
    float2 c7 = *(const float2*)(rb + 14);
    float2 c8 = *(const float2*)(rb + 16);
    float2 c9 = full ? *(const float2*)(rb + 18) : float2{0.f, 0.f};
    float  r20 = full ? rb[20] : 0.f;

    const float D[7] = {e0.x, e0.y, e1.x, e1.y, e2.x, e2.y, d6};
    const float S[7] = {f0.x, f0.y, f1.x, f1.y, f2v.x, f2v.y, s6};
    const float R[7] = {c0.x, c1.y, c3.x, c4.y, c6.x, c7.y, c9.x};
    const float G[7] = {c0.y, c2.x, c3.y, c5.x, c6.y, c8.x, c9.y};
    const float B[7] = {c1.x, c2.y, c4.x, c5.y, c7.x, c8.y, r20};

    // ---- in-lane sequential integration over 6 (or 5) intervals ----
    float u[6];
    float Tloc = 1.0f;
    float Sw = 0.f, Sd = 0.f, Sr = 0.f, Sg = 0.f, Sbv = 0.f;

#define DO_IV(I)                                                      \
    { float delta = D[(I)+1] - D[I];                                  \
      float x = 0.5f * (S[I] + S[(I)+1]) - 1.0f;                      \
      float e = one_minus_alpha(x, delta);                            \
      float uu = (1.0f - e) * Tloc;                                   \
      Tloc *= e + 1e-10f;                                             \
      u[I] = uu;                                                      \
      Sw  += uu;                                                      \
      Sd  += uu * (0.5f * (D[I] + D[(I)+1]));                         \
      Sr  += uu * (0.5f * (R[I] + R[(I)+1]));                         \
      Sg  += uu * (0.5f * (G[I] + G[(I)+1]));                         \
      Sbv += uu * (0.5f * (B[I] + B[(I)+1])); }

    DO_IV(0) DO_IV(1) DO_IV(2) DO_IV(3) DO_IV(4)
    if (full) { DO_IV(5) } else { u[5] = 0.f; }
#undef DO_IV

    // ---- exclusive prefix product of segment transmittances (DPP row scan) ----
    float incl = Tloc;
    incl *= DPPF(1.0f, incl, 0x111);   // row_shr:1
    incl *= DPPF(1.0f, incl, 0x112);   // row_shr:2
    incl *= DPPF(1.0f, incl, 0x114);   // row_shr:4
    incl *= DPPF(1.0f, incl, 0x118);   // row_shr:8
    float Tin = DPPF(1.0f, incl, 0x111);   // shift -> exclusive; lane0 = 1.0

    Sw *= Tin; Sd *= Tin; Sr *= Tin; Sg *= Tin; Sbv *= Tin;

    // ---- row add-reduce: lane 15 ends with the ray totals ----
#define RED(v)                         \
    v += DPPF(0.f, v, 0x111);          \
    v += DPPF(0.f, v, 0x112);          \
    v += DPPF(0.f, v, 0x114);          \
    v += DPPF(0.f, v, 0x118);
    RED(Sw) RED(Sd) RED(Sr) RED(Sg) RED(Sbv)
#undef RED

    // first midpoint (lane 0) -> lane 15 for the depth clip lower bound
    float lo0 = 0.5f * (D[0] + D[1]);
    float lo  = DPPF(0.f, lo0, 0x11F);     // row_shr:15

    // ---- weights output: lanes tile ray*95 + [6l, 6l+6) contiguously ----
    float* wout = out + W_OFF + ray * 95 + 6 * l;
    f4u v4 = { Tin * u[0], Tin * u[1], Tin * u[2], Tin * u[3] };
    *(f4u*)wout = v4;
    if (full) {
        f2u v2 = { Tin * u[4], Tin * u[5] };
        *(f2u*)(wout + 4) = v2;
    } else {
        wout[4] = Tin * u[4];
    }

    // ---- per-ray outputs from lane 15 ----
    if (l == 15) {
        out[RGB_OFF + ray * 3 + 0] = 2.f * Sr  - 1.f;
        out[RGB_OFF + ray * 3 + 1] = 2.f * Sg  - 1.f;
        out[RGB_OFF + ray * 3 + 2] = 2.f * Sbv - 1.f;
        float dv = Sd / Sw;                    // normalize_depth
        float hi = 0.5f * (D[4] + D[5]);       // 0.5*(d[94]+d[95]) on lane 15
        // convex combination => ray-local clip == reference global clip;
        // fminf first so NaN -> hi (matches nan->inf->clip->max)
        dv = fmaxf(fminf(dv, hi), lo);
        out[DEPTH_OFF + ray] = dv;
    }
}

extern "C" void kernel_launch(void* const* d_in, const int* in_sizes, int n_in,
                              void* d_out, int out_size, void* d_ws, size_t ws_size,
                              hipStream_t stream) {
    const float* rgbs   = (const float*)d_in[0];
    const float* sigmas = (const float*)d_in[1];
    const float* depths = (const float*)d_in[2];
    float* out = (float*)d_out;

    // 16 lanes per ray, 16 rays per 256-thread block -> 4096 blocks, 16384 waves
    integrate_kernel<<<NRAYS / 16, 256, 0, stream>>>(rgbs, sigmas, depths, out);
}

// Round 5
// 157.197 us; speedup vs baseline: 1.1311x; 1.0026x over previous
//
#include <hip/hip_runtime.h>
#include <math.h>

// N=4, R=16384, K=96. Output: rgb [65536*3] | depth [65536] | weights [65536*95]
#define NRAYS     65536
#define RGB_OFF   0
#define DEPTH_OFF (NRAYS * 3)
#define W_OFF     (NRAYS * 4)

#define RPB 16               // rays per block (256 threads, 4 waves, 16 lanes/ray)
// LDS layout in floats: depths | sigmas | rgb, padded for lane-15 overreads
#define SHD_OFF 0            // 16*96 = 1536 used, pad to 1540
#define SHS_OFF 1540
#define SHR_OFF 3080         // 16*288 = 4608 used, pad to 4616
#define SH_TOTAL 7696        // 30784 B -> 5 blocks/CU LDS-resident

typedef float f4u __attribute__((ext_vector_type(4), aligned(4)));
typedef float f2u __attribute__((ext_vector_type(2), aligned(4)));

// DPP move within a 16-lane row; invalid source lanes receive `oldv`.
#define DPPF(oldv, x, ctrl)                                                    \
    __int_as_float(__builtin_amdgcn_update_dpp(                                \
        __float_as_int(oldv), __float_as_int(x), (ctrl), 0xF, 0xF, false))

// 1-alpha = exp(-delta*softplus(x)) via HW transcendentals:
// 2^(-delta*log2(1+2^(x*log2e))). Validated absmax 7.8e-3 << 4.3e-2.
__device__ __forceinline__ float one_minus_alpha(float x, float delta) {
    const float L2E = 1.44269504088896340736f;
    float xl = x * L2E;
    float l2 = (x > 20.0f) ? xl
                           : __builtin_amdgcn_logf(1.0f + __builtin_amdgcn_exp2f(xl));
    return __builtin_amdgcn_exp2f(-delta * l2);
}

// async global->LDS, 16 B per lane; LDS dest is wave-uniform base + lane*16,
// which our addressing matches exactly (dst = base + t*16 within each wave).
__device__ __forceinline__ void gload_lds16(const float* g, float* l) {
    __builtin_amdgcn_global_load_lds(
        (const __attribute__((address_space(1))) void*)g,
        (__attribute__((address_space(3))) void*)l, 16, 0, 0);
}

// ---------------------------------------------------------------------------
// R5: R4's compute (16 lanes/ray, in-lane sequential transmittance, DPP row
// scan/reduce -- zero shuffles) + deep-MLP coalesced staging: each block DMAs
// 16 rays (30 KB) to LDS as 30 contiguous 1 KB wave-chunks via
// global_load_lds_dwordx4. 5 blocks/CU resident => ~100+ KB DMA in flight
// per CU, attacking the latency-bound 1.8 TB/s plateau of R4.
// ---------------------------------------------------------------------------
__global__ __launch_bounds__(256) void integrate_kernel(
    const float* __restrict__ rgbs,     // [NRAYS, 96, 3]
    const float* __restrict__ sigmas,   // [NRAYS, 96]
    const float* __restrict__ depths,   // [NRAYS, 96]
    float* __restrict__ out)
{
    __shared__ float sh[SH_TOTAL];

    const int t   = threadIdx.x;
    const int w   = t >> 6;             // wave in block
    const int l64 = t & 63;
    const int blk = blockIdx.x;

    // ---- async staging: 30 wave-chunks of 1024 B, round-robin over 4 waves ----
    {
        const float* gd = depths + (size_t)blk * (RPB * 96);
        const float* gs = sigmas + (size_t)blk * (RPB * 96);
        const float* gr = rgbs   + (size_t)blk * (RPB * 288);
        for (int c = w; c < 30; c += 4) {
            const float* src;
            float* dst;
            if (c < 6)       { src = gd + c * 256;        dst = sh + SHD_OFF + c * 256; }
            else if (c < 12) { src = gs + (c - 6) * 256;  dst = sh + SHS_OFF + (c - 6) * 256; }
            else             { src = gr + (c - 12) * 256; dst = sh + SHR_OFF + (c - 12) * 256; }
            gload_lds16(src + l64 * 4, dst + l64 * 4);
        }
    }
    __builtin_amdgcn_s_waitcnt(0x0F70);   // vmcnt(0) only
    __syncthreads();

    // ---- fragment reads from LDS (b64 granule, no masks -- pad covers tails) ----
    const int rb_ = t >> 4;             // ray within block, 0..15
    const int l   = t & 15;             // segment within ray
    const int ray = blk * RPB + rb_;
    const bool full = (l < 15);

    const float* db = sh + SHD_OFF + rb_ * 96  + 6 * l;
    const float* sp = sh + SHS_OFF + rb_ * 96  + 6 * l;
    const float* rp = sh + SHR_OFF + rb_ * 288 + 18 * l;

    float2 e0 = *(const float2*)(db);
    float2 e1 = *(const float2*)(db + 2);
    float2 e2 = *(const float2*)(db + 4);
    float2 e3 = *(const float2*)(db + 6);
    float2 f0 = *(const float2*)(sp);
    float2 f1 = *(const float2*)(sp + 2);
    float2 f2v = *(const float2*)(sp + 4);
    float2 f3 = *(const float2*)(sp + 6);
    float2 c0 = *(const float2*)(rp);
    float2 c1 = *(const float2*)(rp + 2);
    float2 c2 = *(const float2*)(rp + 4);
    float2 c3 = *(const float2*)(rp + 6);
    float2 c4 = *(const float2*)(rp + 8);
    float2 c5 = *(const float2*)(rp + 10);
    float2 c6 = *(const float2*)(rp + 12);
    float2 c7 = *(const float2*)(rp + 14);
    float2 c8 = *(const float2*)(rp + 16);
    float2 c9 = *(const float2*)(rp + 18);
    float  r20 = rp[20];

    const float D[7] = {e0.x, e0.y, e1.x, e1.y, e2.x, e2.y, e3.x};
    const float S[7] = {f0.x, f0.y, f1.x, f1.y, f2v.x, f2v.y, f3.x};
    const float R[7] = {c0.x, c1.y, c3.x, c4.y, c6.x, c7.y, c9.x};
    const float G[7] = {c0.y, c2.x, c3.y, c5.x, c6.y, c8.x, c9.y};
    const float B[7] = {c1.x, c2.y, c4.x, c5.y, c7.x, c8.y, r20};

    // ---- in-lane sequential integration over 6 (5 on lane 15) intervals ----
    float u[6];
    float Tloc = 1.0f;
    float Sw = 0.f, Sd = 0.f, Sr = 0.f, Sg = 0.f, Sbv = 0.f;

#define DO_IV(I)                                                      \
    { float delta = D[(I)+1] - D[I];                                  \
      float x = 0.5f * (S[I] + S[(I)+1]) - 1.0f;                      \
      float e = one_minus_alpha(x, delta);                            \
      float uu = (1.0f - e) * Tloc;                                   \
      Tloc *= e + 1e-10f;                                             \
      u[I] = uu;                                                      \
      Sw  += uu;                                                      \
      Sd  += uu * (0.5f * (D[I] + D[(I)+1]));                         \
      Sr  += uu * (0.5f * (R[I] + R[(I)+1]));                         \
      Sg  += uu * (0.5f * (G[I] + G[(I)+1]));                         \
      Sbv += uu * (0.5f * (B[I] + B[(I)+1])); }

    DO_IV(0) DO_IV(1) DO_IV(2) DO_IV(3) DO_IV(4)
    if (full) { DO_IV(5) } else { u[5] = 0.f; }
#undef DO_IV

    // ---- exclusive prefix product of segment transmittances (DPP row scan) ----
    float incl = Tloc;
    incl *= DPPF(1.0f, incl, 0x111);   // row_shr:1
    incl *= DPPF(1.0f, incl, 0x112);   // row_shr:2
    incl *= DPPF(1.0f, incl, 0x114);   // row_shr:4
    incl *= DPPF(1.0f, incl, 0x118);   // row_shr:8
    float Tin = DPPF(1.0f, incl, 0x111);   // shift -> exclusive; lane0 = 1.0

    Sw *= Tin; Sd *= Tin; Sr *= Tin; Sg *= Tin; Sbv *= Tin;

    // ---- row add-reduce: lane 15 ends with the ray totals ----
#define RED(v)                         \
    v += DPPF(0.f, v, 0x111);          \
    v += DPPF(0.f, v, 0x112);          \
    v += DPPF(0.f, v, 0x114);          \
    v += DPPF(0.f, v, 0x118);
    RED(Sw) RED(Sd) RED(Sr) RED(Sg) RED(Sbv)
#undef RED

    // first midpoint (lane 0) -> lane 15 for the depth clip lower bound
    float lo0 = 0.5f * (D[0] + D[1]);
    float lo  = DPPF(0.f, lo0, 0x11F);     // row_shr:15

    // ---- weights output: lanes tile ray*95 + [6l, 6l+6) contiguously ----
    float* wout = out + W_OFF + (size_t)ray * 95 + 6 * l;
    f4u v4 = { Tin * u[0], Tin * u[1], Tin * u[2], Tin * u[3] };
    *(f4u*)wout = v4;
    if (full) {
        f2u v2 = { Tin * u[4], Tin * u[5] };
        *(f2u*)(wout + 4) = v2;
    } else {
        wout[4] = Tin * u[4];
    }

    // ---- per-ray outputs from lane 15 ----
    if (l == 15) {
        out[RGB_OFF + ray * 3 + 0] = 2.f * Sr  - 1.f;
        out[RGB_OFF + ray * 3 + 1] = 2.f * Sg  - 1.f;
        out[RGB_OFF + ray * 3 + 2] = 2.f * Sbv - 1.f;
        float dv = Sd / Sw;                    // normalize_depth
        float hi = 0.5f * (D[4] + D[5]);       // 0.5*(d[94]+d[95]) on lane 15
        // convex combination => ray-local clip == reference global clip;
        // fminf first so NaN -> hi (matches nan->inf->clip->max)
        dv = fmaxf(fminf(dv, hi), lo);
        out[DEPTH_OFF + ray] = dv;
    }
}

extern "C" void kernel_launch(void* const* d_in, const int* in_sizes, int n_in,
                              void* d_out, int out_size, void* d_ws, size_t ws_size,
                              hipStream_t stream) {
    const float* rgbs   = (const float*)d_in[0];
    const float* sigmas = (const float*)d_in[1];
    const float* depths = (const float*)d_in[2];
    float* out = (float*)d_out;

    // 16 rays per 256-thread block -> 4096 blocks
    integrate_kernel<<<NRAYS / RPB, 256, 0, stream>>>(rgbs, sigmas, depths, out);
}